// Round 10
// baseline (236.683 us; speedup 1.0000x reference)
//
#include <hip/hip_runtime.h>
#include <hip/hip_fp16.h>

#define NMESH 128
#define NMESH2 (128 * 128)
#define NMESH3 (128 * 128 * 128)
#define NPOINTS 100000
#define NCH 16
#define TILE 1024   // cells per block in the transpose

// ---------------------------------------------------------------------------
// Kernel 1 (v7): transpose (C,X,Y,Z) fp32 -> (X,Y,Z,C) fp16 via LDS bounce.
// Same verified mechanics as v3/v6 (conflict-free LDS, coalesced 16 B/lane on
// both global sides) but 4x LONGER PER-STREAM BURSTS: each block reads 4 KB
// contiguous per channel plane (vs 1 KB in v3/v6) before hopping the 64 MiB
// plane stride -- attacks DRAM page-locality, the one untested pattern var.
// Tile = 1024 cells, 256 threads, 64 KB LDS -> 2 blocks/CU. Grid 2048.
// ---------------------------------------------------------------------------
__global__ __launch_bounds__(256) void transpose_to_half_v7(
    const float* __restrict__ in,   // [16][2M]
    __half* __restrict__ outT)      // [2M][16]
{
    __shared__ float lds[NCH * TILE];   // 64 KB, [c][1024]
    const int t = threadIdx.x;
    const int s_base = blockIdx.x * TILE;

    // Read phase: channel c's 1024 floats = 4 KB contiguous; one dwordx4 per
    // thread per channel. Hoist 8 loads (128 B) in flight, then LDS-stage.
#pragma unroll
    for (int g = 0; g < 2; ++g) {
        float4 v[8];
#pragma unroll
        for (int j = 0; j < 8; ++j) {
            const int c = g * 8 + j;
            v[j] = *(const float4*)(in + (size_t)c * NMESH3 + s_base + 4 * t);
        }
#pragma unroll
        for (int j = 0; j < 8; ++j) {
            const int c = g * 8 + j;
            *(float4*)&lds[c * TILE + 4 * t] = v[j];   // ds_write_b128
        }
    }
    __syncthreads();

    // Store phase: 1024 cells x 32 B = 32 KB contiguous per block.
    // uint4 i covers cell s = i>>1, channels h..h+7 (h=(i&1)*8).
    // LDS reads: 2 lanes/bank (free, m136), same structure as v3.
    uint4* o = (uint4*)(outT + (size_t)s_base * NCH);   // 2048 uint4 per tile
#pragma unroll
    for (int r = 0; r < 8; ++r) {
        const int i = t + 256 * r;
        const int s = i >> 1;
        const int h = (i & 1) * 8;
        uint32_t w[4];
#pragma unroll
        for (int m = 0; m < 4; ++m) {
            const float f0 = lds[(h + 2 * m + 0) * TILE + s];
            const float f1 = lds[(h + 2 * m + 1) * TILE + s];
            w[m] = (uint32_t)__half_as_ushort(__float2half(f0)) |
                   ((uint32_t)__half_as_ushort(__float2half(f1)) << 16);
        }
        o[i] = make_uint4(w[0], w[1], w[2], w[3]);
    }
}

// ---------------------------------------------------------------------------
// Kernel 2 (round-5 version, ~16 us by elimination): gather from transposed
// fp16 mesh. 4 lanes per point, lane owns channel quad; 8 B dwordx2 per tap;
// coalesced float4 output store.
// ---------------------------------------------------------------------------
__global__ __launch_bounds__(256) void gather_half_quad_kernel(
    const __half* __restrict__ meshT,  // [2M][16]
    const float* __restrict__ pts,     // [100000][3]
    float4* __restrict__ out)          // [100000][4] of float4
{
    const int tid = blockIdx.x * 256 + threadIdx.x;
    const int q = tid & 3;   // channel quad
    const int p = tid >> 2;  // point
    if (p >= NPOINTS) return;

    const float SP = 0.1f;
    const float pcx = pts[p * 3 + 0] / SP;
    const float pcy = pts[p * 3 + 1] / SP;
    const float pcz = pts[p * 3 + 2] / SP;

    const int rx = (int)rintf(pcx);
    const int ry = (int)rintf(pcy);
    const int rz = (int)rintf(pcz);

    const float dx = pcx - (float)rx;
    const float dy = pcy - (float)ry;
    const float dz = pcz - (float)rz;

    float wX[3], wY[3], wZ[3];
    wX[0] = (2.0f * dx - 1.0f) * (2.0f * dx - 1.0f) * 0.125f;
    wX[1] = 0.75f - dx * dx;
    wX[2] = (2.0f * dx + 1.0f) * (2.0f * dx + 1.0f) * 0.125f;
    wY[0] = (2.0f * dy - 1.0f) * (2.0f * dy - 1.0f) * 0.125f;
    wY[1] = 0.75f - dy * dy;
    wY[2] = (2.0f * dy + 1.0f) * (2.0f * dy + 1.0f) * 0.125f;
    wZ[0] = (2.0f * dz - 1.0f) * (2.0f * dz - 1.0f) * 0.125f;
    wZ[1] = 0.75f - dz * dz;
    wZ[2] = (2.0f * dz + 1.0f) * (2.0f * dz + 1.0f) * 0.125f;

    int xo[3], yo[3], zq[3];
#pragma unroll
    for (int k = 0; k < 3; ++k) {
        xo[k] = ((rx - 1 + k) & (NMESH - 1)) * (NMESH2 * NCH);
        yo[k] = ((ry - 1 + k) & (NMESH - 1)) * (NMESH * NCH);
        zq[k] = ((rz - 1 + k) & (NMESH - 1)) * NCH + q * 4;
    }

    float4 acc = make_float4(0.0f, 0.0f, 0.0f, 0.0f);
#pragma unroll
    for (int a = 0; a < 3; ++a) {
#pragma unroll
        for (int b = 0; b < 3; ++b) {
            const __half* __restrict__ base = meshT + xo[a] + yo[b];
            const float wxy = wX[a] * wY[b];
#pragma unroll
            for (int k = 0; k < 3; ++k) {
                union { uint2 u; __half2 h[2]; } d;
                d.u = *(const uint2*)(base + zq[k]);
                const float2 f01 = __half22float2(d.h[0]);
                const float2 f23 = __half22float2(d.h[1]);
                const float w = wxy * wZ[k];
                acc.x = fmaf(f01.x, w, acc.x);
                acc.y = fmaf(f01.y, w, acc.y);
                acc.z = fmaf(f23.x, w, acc.z);
                acc.w = fmaf(f23.y, w, acc.w);
            }
        }
    }

    out[tid] = acc;
}

// ---------------------------------------------------------------------------
// Fallback in case ws_size is too small for the fp16 mesh.
// ---------------------------------------------------------------------------
__global__ __launch_bounds__(256) void mesh_interp_fallback_kernel(
    const float* __restrict__ mesh,
    const float* __restrict__ pts,
    float* __restrict__ out)
{
    const int tid = blockIdx.x * 256 + threadIdx.x;
    const int c = tid & (NCH - 1);
    const int p = tid >> 4;
    if (p >= NPOINTS) return;

    const float SP = 0.1f;
    const float pcx = pts[p * 3 + 0] / SP;
    const float pcy = pts[p * 3 + 1] / SP;
    const float pcz = pts[p * 3 + 2] / SP;

    const int rx = (int)rintf(pcx);
    const int ry = (int)rintf(pcy);
    const int rz = (int)rintf(pcz);

    const float dx = pcx - (float)rx;
    const float dy = pcy - (float)ry;
    const float dz = pcz - (float)rz;

    float wX[3], wY[3], wZ[3];
    wX[0] = (2.0f * dx - 1.0f) * (2.0f * dx - 1.0f) * 0.125f;
    wX[1] = 0.75f - dx * dx;
    wX[2] = (2.0f * dx + 1.0f) * (2.0f * dx + 1.0f) * 0.125f;
    wY[0] = (2.0f * dy - 1.0f) * (2.0f * dy - 1.0f) * 0.125f;
    wY[1] = 0.75f - dy * dy;
    wY[2] = (2.0f * dy + 1.0f) * (2.0f * dy + 1.0f) * 0.125f;
    wZ[0] = (2.0f * dz - 1.0f) * (2.0f * dz - 1.0f) * 0.125f;
    wZ[1] = 0.75f - dz * dz;
    wZ[2] = (2.0f * dz + 1.0f) * (2.0f * dz + 1.0f) * 0.125f;

    int xb[3], yb[3], zi[3];
#pragma unroll
    for (int k = 0; k < 3; ++k) {
        xb[k] = ((rx - 1 + k) & (NMESH - 1)) * NMESH2;
        yb[k] = ((ry - 1 + k) & (NMESH - 1)) * NMESH;
        zi[k] = ((rz - 1 + k) & (NMESH - 1));
    }

    const float* __restrict__ mc = mesh + (size_t)c * NMESH3;
    float acc = 0.0f;
#pragma unroll
    for (int a = 0; a < 3; ++a) {
#pragma unroll
        for (int b = 0; b < 3; ++b) {
            const float* __restrict__ row = mc + xb[a] + yb[b];
            const float wxy = wX[a] * wY[b];
            acc = fmaf(row[zi[0]], wxy * wZ[0], acc);
            acc = fmaf(row[zi[1]], wxy * wZ[1], acc);
            acc = fmaf(row[zi[2]], wxy * wZ[2], acc);
        }
    }
    out[tid] = acc;
}

extern "C" void kernel_launch(void* const* d_in, const int* in_sizes, int n_in,
                              void* d_out, int out_size, void* d_ws, size_t ws_size,
                              hipStream_t stream) {
    const float* mesh = (const float*)d_in[0];
    const float* pts  = (const float*)d_in[1];

    const size_t needed = (size_t)NMESH3 * NCH * sizeof(__half);  // 64 MiB

    if (ws_size >= needed) {
        __half* meshT = (__half*)d_ws;
        transpose_to_half_v7<<<NMESH3 / TILE, 256, 0, stream>>>(mesh, meshT);
        const int total = NPOINTS * 4;  // 4 lanes per point (channel quads)
        gather_half_quad_kernel<<<(total + 255) / 256, 256, 0, stream>>>(
            meshT, pts, (float4*)d_out);
    } else {
        const int total = NPOINTS * NCH;
        mesh_interp_fallback_kernel<<<(total + 255) / 256, 256, 0, stream>>>(
            mesh, pts, (float*)d_out);
    }
}

// Round 11
// 233.413 us; speedup vs baseline: 1.0140x; 1.0140x over previous
//
#include <hip/hip_runtime.h>
#include <hip/hip_fp16.h>

#define NMESH 128
#define NMESH2 (128 * 128)
#define NMESH3 (128 * 128 * 128)
#define NPOINTS 100000
#define NCH 16

typedef unsigned int __attribute__((ext_vector_type(4))) u32x4;

// ---------------------------------------------------------------------------
// Kernel 1 (v8): transpose (C,X,Y,Z) fp32 -> (X,Y,Z,C) fp16 via LDS bounce.
// EXACTLY v6 (best measured: 2 tiles/block, 8 hoisted dwordx4 loads,
// conflict-free LDS, 1KB-contiguous uint4 stores) with ONE change:
// NONTEMPORAL STORES ONLY. Loads stay cached (half the mesh reads hit L3 --
// round-10 counters: FETCH 65.5MB of 128MiB). Tests whether streaming 64 MiB
// of dirty lines through the 4 MiB/XCD L2 (write-allocate churn) is what
// throttles the mixed read+write stream to ~3 TB/s.
// Grid 4096 blocks x 256 threads; 32 KB LDS -> 5 blocks/CU.
// ---------------------------------------------------------------------------
__global__ __launch_bounds__(256) void transpose_to_half_v8(
    const float* __restrict__ in,   // [16][2M]
    __half* __restrict__ outT)      // [2M][16]
{
    __shared__ float lds[2][NCH * 256];   // 2 tiles x 16 KB
    const int t = threadIdx.x;
    const int s_base = blockIdx.x * 512;
    const int f = t & 63;      // float4 index within a channel row
    const int c0 = t >> 6;     // 0..3

    // ---- hoisted load phase: 8 independent dwordx4 loads, all in flight ----
    float4 v[2][4];
#pragma unroll
    for (int u = 0; u < 2; ++u) {
#pragma unroll
        for (int k = 0; k < 4; ++k) {
            const int c = c0 + 4 * k;
            v[u][k] = *(const float4*)(in + (size_t)c * NMESH3 + s_base +
                                       u * 256 + 4 * f);
        }
    }

    // ---- LDS stage (conflict-free: v3 pattern) ----
#pragma unroll
    for (int u = 0; u < 2; ++u) {
#pragma unroll
        for (int k = 0; k < 4; ++k) {
            const int c = c0 + 4 * k;
            *(float4*)&lds[u][c * 256 + 4 * f] = v[u][k];   // ds_write_b128
        }
    }
    __syncthreads();

    // ---- store phase: per tile, vec4 i covers cell s=i>>1, ch h..h+7 ----
#pragma unroll
    for (int u = 0; u < 2; ++u) {
        u32x4* o = (u32x4*)(outT + (size_t)(s_base + u * 256) * NCH);
#pragma unroll
        for (int r = 0; r < 2; ++r) {
            const int i = t + 256 * r;
            const int s = i >> 1;
            const int h = (i & 1) * 8;
            u32x4 w;
#pragma unroll
            for (int m = 0; m < 4; ++m) {
                const float f0 = lds[u][(h + 2 * m + 0) * 256 + s];
                const float f1 = lds[u][(h + 2 * m + 1) * 256 + s];
                w[m] = (uint32_t)__half_as_ushort(__float2half(f0)) |
                       ((uint32_t)__half_as_ushort(__float2half(f1)) << 16);
            }
            __builtin_nontemporal_store(w, &o[i]);   // nt STORE only
        }
    }
}

// ---------------------------------------------------------------------------
// Kernel 2 (round-5 version, ~16 us by elimination): gather from transposed
// fp16 mesh. 4 lanes per point, lane owns channel quad; 8 B dwordx2 per tap;
// coalesced float4 output store.
// ---------------------------------------------------------------------------
__global__ __launch_bounds__(256) void gather_half_quad_kernel(
    const __half* __restrict__ meshT,  // [2M][16]
    const float* __restrict__ pts,     // [100000][3]
    float4* __restrict__ out)          // [100000][4] of float4
{
    const int tid = blockIdx.x * 256 + threadIdx.x;
    const int q = tid & 3;   // channel quad
    const int p = tid >> 2;  // point
    if (p >= NPOINTS) return;

    const float SP = 0.1f;
    const float pcx = pts[p * 3 + 0] / SP;
    const float pcy = pts[p * 3 + 1] / SP;
    const float pcz = pts[p * 3 + 2] / SP;

    const int rx = (int)rintf(pcx);
    const int ry = (int)rintf(pcy);
    const int rz = (int)rintf(pcz);

    const float dx = pcx - (float)rx;
    const float dy = pcy - (float)ry;
    const float dz = pcz - (float)rz;

    float wX[3], wY[3], wZ[3];
    wX[0] = (2.0f * dx - 1.0f) * (2.0f * dx - 1.0f) * 0.125f;
    wX[1] = 0.75f - dx * dx;
    wX[2] = (2.0f * dx + 1.0f) * (2.0f * dx + 1.0f) * 0.125f;
    wY[0] = (2.0f * dy - 1.0f) * (2.0f * dy - 1.0f) * 0.125f;
    wY[1] = 0.75f - dy * dy;
    wY[2] = (2.0f * dy + 1.0f) * (2.0f * dy + 1.0f) * 0.125f;
    wZ[0] = (2.0f * dz - 1.0f) * (2.0f * dz - 1.0f) * 0.125f;
    wZ[1] = 0.75f - dz * dz;
    wZ[2] = (2.0f * dz + 1.0f) * (2.0f * dz + 1.0f) * 0.125f;

    int xo[3], yo[3], zq[3];
#pragma unroll
    for (int k = 0; k < 3; ++k) {
        xo[k] = ((rx - 1 + k) & (NMESH - 1)) * (NMESH2 * NCH);
        yo[k] = ((ry - 1 + k) & (NMESH - 1)) * (NMESH * NCH);
        zq[k] = ((rz - 1 + k) & (NMESH - 1)) * NCH + q * 4;
    }

    float4 acc = make_float4(0.0f, 0.0f, 0.0f, 0.0f);
#pragma unroll
    for (int a = 0; a < 3; ++a) {
#pragma unroll
        for (int b = 0; b < 3; ++b) {
            const __half* __restrict__ base = meshT + xo[a] + yo[b];
            const float wxy = wX[a] * wY[b];
#pragma unroll
            for (int k = 0; k < 3; ++k) {
                union { uint2 u; __half2 h[2]; } d;
                d.u = *(const uint2*)(base + zq[k]);
                const float2 f01 = __half22float2(d.h[0]);
                const float2 f23 = __half22float2(d.h[1]);
                const float w = wxy * wZ[k];
                acc.x = fmaf(f01.x, w, acc.x);
                acc.y = fmaf(f01.y, w, acc.y);
                acc.z = fmaf(f23.x, w, acc.z);
                acc.w = fmaf(f23.y, w, acc.w);
            }
        }
    }

    out[tid] = acc;
}

// ---------------------------------------------------------------------------
// Fallback in case ws_size is too small for the fp16 mesh.
// ---------------------------------------------------------------------------
__global__ __launch_bounds__(256) void mesh_interp_fallback_kernel(
    const float* __restrict__ mesh,
    const float* __restrict__ pts,
    float* __restrict__ out)
{
    const int tid = blockIdx.x * 256 + threadIdx.x;
    const int c = tid & (NCH - 1);
    const int p = tid >> 4;
    if (p >= NPOINTS) return;

    const float SP = 0.1f;
    const float pcx = pts[p * 3 + 0] / SP;
    const float pcy = pts[p * 3 + 1] / SP;
    const float pcz = pts[p * 3 + 2] / SP;

    const int rx = (int)rintf(pcx);
    const int ry = (int)rintf(pcy);
    const int rz = (int)rintf(pcz);

    const float dx = pcx - (float)rx;
    const float dy = pcy - (float)ry;
    const float dz = pcz - (float)rz;

    float wX[3], wY[3], wZ[3];
    wX[0] = (2.0f * dx - 1.0f) * (2.0f * dx - 1.0f) * 0.125f;
    wX[1] = 0.75f - dx * dx;
    wX[2] = (2.0f * dx + 1.0f) * (2.0f * dx + 1.0f) * 0.125f;
    wY[0] = (2.0f * dy - 1.0f) * (2.0f * dy - 1.0f) * 0.125f;
    wY[1] = 0.75f - dy * dy;
    wY[2] = (2.0f * dy + 1.0f) * (2.0f * dy + 1.0f) * 0.125f;
    wZ[0] = (2.0f * dz - 1.0f) * (2.0f * dz - 1.0f) * 0.125f;
    wZ[1] = 0.75f - dz * dz;
    wZ[2] = (2.0f * dz + 1.0f) * (2.0f * dz + 1.0f) * 0.125f;

    int xb[3], yb[3], zi[3];
#pragma unroll
    for (int k = 0; k < 3; ++k) {
        xb[k] = ((rx - 1 + k) & (NMESH - 1)) * NMESH2;
        yb[k] = ((ry - 1 + k) & (NMESH - 1)) * NMESH;
        zi[k] = ((rz - 1 + k) & (NMESH - 1));
    }

    const float* __restrict__ mc = mesh + (size_t)c * NMESH3;
    float acc = 0.0f;
#pragma unroll
    for (int a = 0; a < 3; ++a) {
#pragma unroll
        for (int b = 0; b < 3; ++b) {
            const float* __restrict__ row = mc + xb[a] + yb[b];
            const float wxy = wX[a] * wY[b];
            acc = fmaf(row[zi[0]], wxy * wZ[0], acc);
            acc = fmaf(row[zi[1]], wxy * wZ[1], acc);
            acc = fmaf(row[zi[2]], wxy * wZ[2], acc);
        }
    }
    out[tid] = acc;
}

extern "C" void kernel_launch(void* const* d_in, const int* in_sizes, int n_in,
                              void* d_out, int out_size, void* d_ws, size_t ws_size,
                              hipStream_t stream) {
    const float* mesh = (const float*)d_in[0];
    const float* pts  = (const float*)d_in[1];

    const size_t needed = (size_t)NMESH3 * NCH * sizeof(__half);  // 64 MiB

    if (ws_size >= needed) {
        __half* meshT = (__half*)d_ws;
        transpose_to_half_v8<<<NMESH3 / 512, 256, 0, stream>>>(mesh, meshT);
        const int total = NPOINTS * 4;  // 4 lanes per point (channel quads)
        gather_half_quad_kernel<<<(total + 255) / 256, 256, 0, stream>>>(
            meshT, pts, (float4*)d_out);
    } else {
        const int total = NPOINTS * NCH;
        mesh_interp_fallback_kernel<<<(total + 255) / 256, 256, 0, stream>>>(
            mesh, pts, (float*)d_out);
    }
}

// Round 12
// 225.733 us; speedup vs baseline: 1.0485x; 1.0340x over previous
//
#include <hip/hip_runtime.h>
#include <hip/hip_fp16.h>

#define NMESH 128
#define NMESH2 (128 * 128)
#define NMESH3 (128 * 128 * 128)
#define NPOINTS 100000
#define NCH 16

// ---------------------------------------------------------------------------
// Kernel 1 (v6 -- best measured config, 224.6 us total): transpose
// (C,X,Y,Z) fp32 -> (X,Y,Z,C) fp16 via LDS bounce.
// 2 tiles per block, all 8 dwordx4 loads hoisted before any LDS write
// (128 B in flight/thread), conflict-free LDS, 1KB-contiguous uint4 stores,
// cached (non-nt) on both sides: loads get ~50% L3 hits (round-10 FETCH
// data), stores keep meshT cache-resident for the gather.
// Grid 4096 blocks x 256 threads; 32 KB LDS -> 5 blocks/CU.
//
// Falsified single-lever variants (rounds 2-11): wider/narrower tiles, no-LDS
// register transpose, persistent grid + dbuf + channel rotation, nt loads,
// nt stores, 4KB bursts. All null or regressions; this config is the floor.
// ---------------------------------------------------------------------------
__global__ __launch_bounds__(256) void transpose_to_half_v6(
    const float* __restrict__ in,   // [16][2M]
    __half* __restrict__ outT)      // [2M][16]
{
    __shared__ float lds[2][NCH * 256];   // 2 tiles x 16 KB
    const int t = threadIdx.x;
    const int s_base = blockIdx.x * 512;
    const int f = t & 63;      // float4 index within a channel row
    const int c0 = t >> 6;     // 0..3

    // ---- hoisted load phase: 8 independent dwordx4 loads, all in flight ----
    float4 v[2][4];
#pragma unroll
    for (int u = 0; u < 2; ++u) {
#pragma unroll
        for (int k = 0; k < 4; ++k) {
            const int c = c0 + 4 * k;
            v[u][k] = *(const float4*)(in + (size_t)c * NMESH3 + s_base +
                                       u * 256 + 4 * f);
        }
    }

    // ---- LDS stage (conflict-free: v3 pattern) ----
#pragma unroll
    for (int u = 0; u < 2; ++u) {
#pragma unroll
        for (int k = 0; k < 4; ++k) {
            const int c = c0 + 4 * k;
            *(float4*)&lds[u][c * 256 + 4 * f] = v[u][k];   // ds_write_b128
        }
    }
    __syncthreads();

    // ---- store phase: per tile, uint4 i covers cell s=i>>1, ch h..h+7 ----
#pragma unroll
    for (int u = 0; u < 2; ++u) {
        uint4* o = (uint4*)(outT + (size_t)(s_base + u * 256) * NCH);
#pragma unroll
        for (int r = 0; r < 2; ++r) {
            const int i = t + 256 * r;
            const int s = i >> 1;
            const int h = (i & 1) * 8;
            uint32_t w[4];
#pragma unroll
            for (int m = 0; m < 4; ++m) {
                const float f0 = lds[u][(h + 2 * m + 0) * 256 + s];
                const float f1 = lds[u][(h + 2 * m + 1) * 256 + s];
                w[m] = (uint32_t)__half_as_ushort(__float2half(f0)) |
                       ((uint32_t)__half_as_ushort(__float2half(f1)) << 16);
            }
            o[i] = make_uint4(w[0], w[1], w[2], w[3]);
        }
    }
}

// ---------------------------------------------------------------------------
// Kernel 2 (~16 us by elimination): gather from transposed fp16 mesh.
// 4 lanes per point, lane owns channel quad; 8 B dwordx2 per tap;
// coalesced float4 output store.
// ---------------------------------------------------------------------------
__global__ __launch_bounds__(256) void gather_half_quad_kernel(
    const __half* __restrict__ meshT,  // [2M][16]
    const float* __restrict__ pts,     // [100000][3]
    float4* __restrict__ out)          // [100000][4] of float4
{
    const int tid = blockIdx.x * 256 + threadIdx.x;
    const int q = tid & 3;   // channel quad
    const int p = tid >> 2;  // point
    if (p >= NPOINTS) return;

    const float SP = 0.1f;
    const float pcx = pts[p * 3 + 0] / SP;
    const float pcy = pts[p * 3 + 1] / SP;
    const float pcz = pts[p * 3 + 2] / SP;

    const int rx = (int)rintf(pcx);
    const int ry = (int)rintf(pcy);
    const int rz = (int)rintf(pcz);

    const float dx = pcx - (float)rx;
    const float dy = pcy - (float)ry;
    const float dz = pcz - (float)rz;

    float wX[3], wY[3], wZ[3];
    wX[0] = (2.0f * dx - 1.0f) * (2.0f * dx - 1.0f) * 0.125f;
    wX[1] = 0.75f - dx * dx;
    wX[2] = (2.0f * dx + 1.0f) * (2.0f * dx + 1.0f) * 0.125f;
    wY[0] = (2.0f * dy - 1.0f) * (2.0f * dy - 1.0f) * 0.125f;
    wY[1] = 0.75f - dy * dy;
    wY[2] = (2.0f * dy + 1.0f) * (2.0f * dy + 1.0f) * 0.125f;
    wZ[0] = (2.0f * dz - 1.0f) * (2.0f * dz - 1.0f) * 0.125f;
    wZ[1] = 0.75f - dz * dz;
    wZ[2] = (2.0f * dz + 1.0f) * (2.0f * dz + 1.0f) * 0.125f;

    int xo[3], yo[3], zq[3];
#pragma unroll
    for (int k = 0; k < 3; ++k) {
        xo[k] = ((rx - 1 + k) & (NMESH - 1)) * (NMESH2 * NCH);
        yo[k] = ((ry - 1 + k) & (NMESH - 1)) * (NMESH * NCH);
        zq[k] = ((rz - 1 + k) & (NMESH - 1)) * NCH + q * 4;
    }

    float4 acc = make_float4(0.0f, 0.0f, 0.0f, 0.0f);
#pragma unroll
    for (int a = 0; a < 3; ++a) {
#pragma unroll
        for (int b = 0; b < 3; ++b) {
            const __half* __restrict__ base = meshT + xo[a] + yo[b];
            const float wxy = wX[a] * wY[b];
#pragma unroll
            for (int k = 0; k < 3; ++k) {
                union { uint2 u; __half2 h[2]; } d;
                d.u = *(const uint2*)(base + zq[k]);
                const float2 f01 = __half22float2(d.h[0]);
                const float2 f23 = __half22float2(d.h[1]);
                const float w = wxy * wZ[k];
                acc.x = fmaf(f01.x, w, acc.x);
                acc.y = fmaf(f01.y, w, acc.y);
                acc.z = fmaf(f23.x, w, acc.z);
                acc.w = fmaf(f23.y, w, acc.w);
            }
        }
    }

    out[tid] = acc;
}

// ---------------------------------------------------------------------------
// Fallback in case ws_size is too small for the fp16 mesh.
// ---------------------------------------------------------------------------
__global__ __launch_bounds__(256) void mesh_interp_fallback_kernel(
    const float* __restrict__ mesh,
    const float* __restrict__ pts,
    float* __restrict__ out)
{
    const int tid = blockIdx.x * 256 + threadIdx.x;
    const int c = tid & (NCH - 1);
    const int p = tid >> 4;
    if (p >= NPOINTS) return;

    const float SP = 0.1f;
    const float pcx = pts[p * 3 + 0] / SP;
    const float pcy = pts[p * 3 + 1] / SP;
    const float pcz = pts[p * 3 + 2] / SP;

    const int rx = (int)rintf(pcx);
    const int ry = (int)rintf(pcy);
    const int rz = (int)rintf(pcz);

    const float dx = pcx - (float)rx;
    const float dy = pcy - (float)ry;
    const float dz = pcz - (float)rz;

    float wX[3], wY[3], wZ[3];
    wX[0] = (2.0f * dx - 1.0f) * (2.0f * dx - 1.0f) * 0.125f;
    wX[1] = 0.75f - dx * dx;
    wX[2] = (2.0f * dx + 1.0f) * (2.0f * dx + 1.0f) * 0.125f;
    wY[0] = (2.0f * dy - 1.0f) * (2.0f * dy - 1.0f) * 0.125f;
    wY[1] = 0.75f - dy * dy;
    wY[2] = (2.0f * dy + 1.0f) * (2.0f * dy + 1.0f) * 0.125f;
    wZ[0] = (2.0f * dz - 1.0f) * (2.0f * dz - 1.0f) * 0.125f;
    wZ[1] = 0.75f - dz * dz;
    wZ[2] = (2.0f * dz + 1.0f) * (2.0f * dz + 1.0f) * 0.125f;

    int xb[3], yb[3], zi[3];
#pragma unroll
    for (int k = 0; k < 3; ++k) {
        xb[k] = ((rx - 1 + k) & (NMESH - 1)) * NMESH2;
        yb[k] = ((ry - 1 + k) & (NMESH - 1)) * NMESH;
        zi[k] = ((rz - 1 + k) & (NMESH - 1));
    }

    const float* __restrict__ mc = mesh + (size_t)c * NMESH3;
    float acc = 0.0f;
#pragma unroll
    for (int a = 0; a < 3; ++a) {
#pragma unroll
        for (int b = 0; b < 3; ++b) {
            const float* __restrict__ row = mc + xb[a] + yb[b];
            const float wxy = wX[a] * wY[b];
            acc = fmaf(row[zi[0]], wxy * wZ[0], acc);
            acc = fmaf(row[zi[1]], wxy * wZ[1], acc);
            acc = fmaf(row[zi[2]], wxy * wZ[2], acc);
        }
    }
    out[tid] = acc;
}

extern "C" void kernel_launch(void* const* d_in, const int* in_sizes, int n_in,
                              void* d_out, int out_size, void* d_ws, size_t ws_size,
                              hipStream_t stream) {
    const float* mesh = (const float*)d_in[0];
    const float* pts  = (const float*)d_in[1];

    const size_t needed = (size_t)NMESH3 * NCH * sizeof(__half);  // 64 MiB

    if (ws_size >= needed) {
        __half* meshT = (__half*)d_ws;
        transpose_to_half_v6<<<NMESH3 / 512, 256, 0, stream>>>(mesh, meshT);
        const int total = NPOINTS * 4;  // 4 lanes per point (channel quads)
        gather_half_quad_kernel<<<(total + 255) / 256, 256, 0, stream>>>(
            meshT, pts, (float4*)d_out);
    } else {
        const int total = NPOINTS * NCH;
        mesh_interp_fallback_kernel<<<(total + 255) / 256, 256, 0, stream>>>(
            mesh, pts, (float*)d_out);
    }
}